// Round 15
// baseline (97.004 us; speedup 1.0000x reference)
//
#include <hip/hip_runtime.h>

#define NQ 12
#define NLAYERS 8
#define BATCH 1024

typedef float v2f __attribute__((ext_vector_type(2)));

// ---------------------------------------------------------------------------
// R15: ONE WAVE = ONE STATE, ZERO BARRIERS, ZERO __shared__.
// p = (lane<<6)|j ; wire w <-> bit (11-w): lane bits 5..0 = wires 0..5,
// j bits 5..0 = wires 6..11 ; j = 2t+k -> re2[t]/im2[t] (v2f) hold amps 2t,2t+1.
// Per layer: CNOT restore q = p^(p>>1) = gray lane permutation (ds_permute
//   push, addr = gray-decode(lane)) + compile-time j re-index + src-parity
//   cndmask for the lane->j carry bit; then RX w0..w11 (permlane32/16 for
//   w0/w1 [R13-verified], DPP for w2..5, local for w6..11); then fused-RZ
//   diagonal (alpha over lane wires 0..5, precomputed beta_j table) [R12].
// No inter-wave communication at all -> barrier-correlated stalls (the ~25us
// wall/busy gap of R12-R13, confirmed by R14's failure) are gone.
// ---------------------------------------------------------------------------

constexpr int hbit(int m){ int h=0; while(m>>(h+1)) ++h; return 1<<h; }

__device__ __forceinline__ v2f vsplat(float s){ v2f v; v.x=s; v.y=s; return v; }
__device__ __forceinline__ v2f vswap(v2f v){ return __builtin_shufflevector(v, v, 1, 0); }
template<int S> __device__ __forceinline__ v2f msw(v2f v){ if constexpr (S) return vswap(v); else return v; }
__device__ __forceinline__ v2f vfma(v2f a, v2f b, v2f c){ return __builtin_elementwise_fma(a,b,c); }

template<int S>
__device__ __forceinline__ void rx_upd(v2f& ro, v2f& io, v2f r, v2f i, v2f pr, v2f pi,
                                       v2f hc2, v2f hs2, v2f ns2){
    ro = vfma(hc2, r, hs2*msw<S>(pi));
    io = vfma(hc2, i, ns2*msw<S>(pr));
}

#if __has_builtin(__builtin_amdgcn_permlane32_swap) && __has_builtin(__builtin_amdgcn_permlane16_swap)
#define HAVE_PLSWAP 1
#else
#define HAVE_PLSWAP 0
#endif

#if HAVE_PLSWAP
// double-swap (R10/R13-verified): c1 = swap(r,i); c2 = swap(c1[1], c1[0]) ->
//   c2[0] = xorK(r), c2[1] = xorK(i)
__device__ __forceinline__ void xp32(float& pr, float& pi, float r, float i){
    auto c1 = __builtin_amdgcn_permlane32_swap(__float_as_uint(r), __float_as_uint(i), false, false);
    auto c2 = __builtin_amdgcn_permlane32_swap(c1[1], c1[0], false, false);
    pr = __uint_as_float(c2[0]);
    pi = __uint_as_float(c2[1]);
}
__device__ __forceinline__ void xp16(float& pr, float& pi, float r, float i){
    auto c1 = __builtin_amdgcn_permlane16_swap(__float_as_uint(r), __float_as_uint(i), false, false);
    auto c2 = __builtin_amdgcn_permlane16_swap(c1[1], c1[0], false, false);
    pr = __uint_as_float(c2[0]);
    pi = __uint_as_float(c2[1]);
}
#endif

__device__ __forceinline__ float bperm1(int addr, float v){
    return __int_as_float(__builtin_amdgcn_ds_bpermute(addr, __float_as_int(v)));
}

// ---- DPP lane-xor (VALU pipe), LM in [1,15] (R5-proven) ----
template<int CTRL>
__device__ __forceinline__ float dpp1(float v){
    int i = __float_as_int(v);
    return __int_as_float(__builtin_amdgcn_update_dpp(i, i, CTRL, 0xF, 0xF, true));
}
template<int LM>
__device__ __forceinline__ float dppx(float v){
    static_assert(LM >= 1 && LM <= 15, "dpp xor range");
    constexpr int h = (LM >> 2) & 3;
    float r = v;
    if constexpr (h == 1 || h == 2) r = dpp1<0x141>(r);   // row_half_mirror = xor 7
    if constexpr (h == 3 || h == 2) r = dpp1<0x140>(r);   // row_mirror      = xor 15
    constexpr int st = (h==1)?7 : (h==2)?8 : (h==3)?15 : 0;
    constexpr int q = (LM ^ st) & 3;
    if constexpr (q == 1) r = dpp1<0xB1>(r);              // quad_perm xor 1
    if constexpr (q == 2) r = dpp1<0x4E>(r);              // quad_perm xor 2
    if constexpr (q == 3) r = dpp1<0x1B>(r);              // quad_perm xor 3
    return r;
}

// ---- RX, partner fully local (JM = j-space xor mask, j 6-bit) ----
template<int JM>
__device__ __forceinline__ void rx_local32(v2f (&re2)[32], v2f (&im2)[32],
                                           v2f hc2, v2f hs2, v2f ns2){
    if constexpr (JM == 1){
        #pragma unroll
        for (int t=0;t<32;++t){
            v2f r=re2[t], i=im2[t];
            rx_upd<1>(re2[t], im2[t], r, i, r, i, hc2, hs2, ns2);
        }
    } else {
        constexpr int m = JM>>1, HB = hbit(m), S = JM&1;
        #pragma unroll
        for (int t=0;t<32;++t){
            if (t & HB) continue;
            const int t2 = t ^ m;
            v2f ru=re2[t], iu=im2[t], rv=re2[t2], iv=im2[t2];
            rx_upd<S>(re2[t],  im2[t],  ru, iu, rv, iv, hc2, hs2, ns2);
            rx_upd<S>(re2[t2], im2[t2], rv, iv, ru, iu, hc2, hs2, ns2);
        }
    }
}

// ---- canonical RX on wire W (0..11) ----
template<int W>
__device__ __forceinline__ void rx_canon(v2f (&re2)[32], v2f (&im2)[32],
                                         float hc, float hs, int lane){
    const v2f hc2 = vsplat(hc), hs2 = vsplat(hs), ns2 = vsplat(-hs);
    if constexpr (W <= 1){                       // lane bits 5/4
#if HAVE_PLSWAP
        #pragma unroll
        for (int t=0;t<32;++t){
            v2f r=re2[t], i=im2[t];
            float prx,pix,pry,piy;
            if constexpr (W==0){ xp32(prx,pix,r.x,i.x); xp32(pry,piy,r.y,i.y); }
            else               { xp16(prx,pix,r.x,i.x); xp16(pry,piy,r.y,i.y); }
            v2f pr, pi;
            pr.x=prx; pr.y=pry; pi.x=pix; pi.y=piy;
            rx_upd<0>(re2[t], im2[t], r, i, pr, pi, hc2, hs2, ns2);
        }
#else
        const int addr = ((lane ^ (32>>W)) & 63) << 2;
        #pragma unroll
        for (int t=0;t<32;++t){
            v2f r=re2[t], i=im2[t];
            v2f pr, pi;
            pr.x = bperm1(addr, r.x); pr.y = bperm1(addr, r.y);
            pi.x = bperm1(addr, i.x); pi.y = bperm1(addr, i.y);
            rx_upd<0>(re2[t], im2[t], r, i, pr, pi, hc2, hs2, ns2);
        }
#endif
    } else if constexpr (W <= 5){                // lane bits 3..0: DPP
        constexpr int LM = 1<<(5-W);
        #pragma unroll
        for (int t=0;t<32;++t){
            v2f r=re2[t], i=im2[t];
            v2f pr, pi;
            float a0=dppx<LM>(r.x), a1=dppx<LM>(r.y);
            float b0=dppx<LM>(i.x), b1=dppx<LM>(i.y);
            pr.x=a0; pr.y=a1; pi.x=b0; pi.y=b1;
            rx_upd<0>(re2[t], im2[t], r, i, pr, pi, hc2, hs2, ns2);
        }
    } else {                                     // wires 6..11: local
        rx_local32<(1<<(11-W))>(re2, im2, hc2, hs2, ns2);
    }
}

// ---- scalar access to packed state by 6-bit j index (compile-time) ----
template<int J>
__device__ __forceinline__ float getsc(const v2f (&a)[32]){
    if constexpr (J & 1) return a[J>>1].y; else return a[J>>1].x;
}

// ---- CNOT-ladder restore: new[p] = old[p ^ (p>>1)] ----
// lane part: push via ds_permute, dst lane = gray-decode(src lane).
// j part: src jj = j^(j>>1) ^ (parity(srcLane)<<5): candidate select BEFORE
// push by src-lane popcount parity (dst lane parity == src popc parity).
__device__ __forceinline__ void restore_arr(v2f (&a)[32], int pfx_addr, bool pp){
    float n[64];
    #pragma unroll
    for (int j=0;j<64;++j){
        const int ja = j ^ (j>>1);
        const int tA = ja >> 1, tB = tA ^ 16;
        float sA, sB;
        if (ja & 1){ sA = a[tA].y; sB = a[tB].y; }
        else       { sA = a[tA].x; sB = a[tB].x; }
        const float sel = pp ? sB : sA;
        n[j] = __int_as_float(__builtin_amdgcn_ds_permute(pfx_addr, __float_as_int(sel)));
    }
    #pragma unroll
    for (int t=0;t<32;++t){ a[t].x = n[2*t]; a[t].y = n[2*t+1]; }
}

// ---- per-layer RX gates w0..w11 ----
template<int W>
__device__ __forceinline__ void gates_w(v2f (&re2)[32], v2f (&im2)[32],
                                        const float2* __restrict__ tb, int lane){
    const float2 t = tb[W];
    rx_canon<W>(re2, im2, t.x, t.y, lane);
    if constexpr (W+1 < NQ) gates_w<W+1>(re2, im2, tb, lane);
}

// ---- init RX w0..w11 (runtime angles from x) ----
template<int W>
__device__ __forceinline__ void init_w(v2f (&re2)[32], v2f (&im2)[32],
                                       const float* __restrict__ xb, int lane){
    float hs, hc;
    __sincosf(xb[W]*1.5707963267948966f, &hs, &hc);
    rx_canon<W>(re2, im2, hc, hs, lane);
    if constexpr (W+1 < NQ) init_w<W+1>(re2, im2, xb, lane);
}

// ---------------------------------------------------------------------------
// Workspace (floats): [0,192) tRX float2[8][12]; [192,256) tTH float[8][8]
// (RZ th/2, wires 0..5 used); [256,1280) tJ float4[8][32]
// (cos b_{2t}, cos b_{2t+1}, sin b_{2t}, sin b_{2t+1}) for wires 6..11.
// ---------------------------------------------------------------------------
__global__ void prep_kernel(const float* __restrict__ P, float* __restrict__ ws){
    const int i = threadIdx.x;   // 256 threads
    float2* tRX = (float2*)ws;
    float*  tTH = ws + 192;
    float4* tJ  = (float4*)(ws + 256);
    if (i < 96){
        const int l = i/12, w = i%12;
        float2 v; __sincosf(P[l*24 + 2*w]*0.5f, &v.y, &v.x);
        tRX[i] = v;
    }
    if (i < 64){
        const int l = i>>3, w = i&7;
        tTH[i] = (w < 6) ? P[l*24 + 2*w + 1]*0.5f : 0.f;
    }
    {
        const int l = i>>5, t = i&31;
        float br[2], bi[2];
        #pragma unroll
        for (int k=0;k<2;++k){
            const int j = 2*t + k;
            float beta = 0.f;
            #pragma unroll
            for (int w=6; w<12; ++w){
                const float th = P[l*24 + 2*w + 1]*0.5f;
                beta += ((j >> (11-w)) & 1) ? th : -th;
            }
            __sincosf(beta, &bi[k], &br[k]);
        }
        float4 v; v.x=br[0]; v.y=br[1]; v.z=bi[0]; v.w=bi[1];
        tJ[l*32 + t] = v;
    }
}

__global__ __launch_bounds__(256, 1) void qnn_kernel(const float* __restrict__ x,
                                                     const float* __restrict__ ws,
                                                     const float* __restrict__ Wm,
                                                     float* __restrict__ out)
{
    const int lane = threadIdx.x & 63;
    const int wid  = threadIdx.x >> 6;
    const int b    = blockIdx.x*4 + wid;

    const float2* tRX = (const float2*)ws;
    const float*  tTH = ws + 192;
    const float4* tJ  = (const float4*)(ws + 256);

    // gray-decode(lane) = prefix-xor; push addr for ds_permute
    int pf = lane; pf ^= pf>>1; pf ^= pf>>2; pf ^= pf>>4;
    const int pfx_addr = (pf & 63) << 2;
    const bool pp = (__popc(lane) & 1) != 0;

    v2f re2[32], im2[32];
    #pragma unroll
    for (int t=0;t<32;++t){ re2[t] = vsplat(0.f); im2[t] = vsplat(0.f); }
    if (lane == 0) re2[0].x = 1.0f;

    init_w<0>(re2, im2, x + b*NQ, lane);

    #pragma unroll 1
    for (int l = 0; l < NLAYERS; ++l){
        restore_arr(re2, pfx_addr, pp);           // CNOT ladder (lane+reg permute)
        restore_arr(im2, pfx_addr, pp);
        gates_w<0>(re2, im2, tRX + l*12, lane);   // RX w0..w11

        // ---- fused RZ (all 12 wires) ----
        const float* th = tTH + l*8;
        float alpha = 0.f;
        #pragma unroll
        for (int w=0; w<=5; ++w)
            alpha += ((lane >> (5-w)) & 1) ? th[w] : -th[w];
        float sa, ca;
        __sincosf(alpha, &sa, &ca);
        const v2f vca = vsplat(ca), vsa = vsplat(sa), vna = vsplat(-sa);
        const float4* tj = tJ + l*32;
        #pragma unroll
        for (int t=0;t<32;++t){
            const float4 J = tj[t];
            v2f jr; jr.x=J.x; jr.y=J.y;
            v2f ji; ji.x=J.z; ji.y=J.w;
            const v2f cr  = vfma(vca, jr, vna*ji);   // cos(a+b)
            const v2f ci  = vfma(vca, ji, vsa*jr);   // sin(a+b)
            const v2f nci = -ci;
            const v2f r = re2[t], m = im2[t];
            re2[t] = vfma(r, cr, m*nci);
            im2[t] = vfma(m, cr, r*ci);
        }
    }

    // ---- PauliZ expvals (canonical state) ----
    v2f S = vsplat(0.f), S6 = vsplat(0.f), S7 = vsplat(0.f), S8 = vsplat(0.f),
        S9 = vsplat(0.f), S10 = vsplat(0.f);
    #pragma unroll
    for (int t=0;t<32;++t){
        v2f p2 = __builtin_elementwise_fma(re2[t], re2[t], im2[t]*im2[t]);
        S += p2;
        S6  += (t&16)? -p2 : p2;   // wire 6  (t bit4)
        S7  += (t& 8)? -p2 : p2;   // wire 7
        S8  += (t& 4)? -p2 : p2;   // wire 8
        S9  += (t& 2)? -p2 : p2;   // wire 9
        S10 += (t& 1)? -p2 : p2;   // wire 10
    }
    const float s0 = S.x + S.y;

    float z[12];
    #pragma unroll
    for (int w=0; w<=5; ++w) z[w] = ((lane >> (5-w)) & 1) ? -s0 : s0;
    z[6]  = S6.x + S6.y;
    z[7]  = S7.x + S7.y;
    z[8]  = S8.x + S8.y;
    z[9]  = S9.x + S9.y;
    z[10] = S10.x + S10.y;
    z[11] = S.x - S.y;             // wire 11 (component)

    #pragma unroll
    for (int m=1; m<64; m<<=1){
        #pragma unroll
        for (int w=0; w<12; ++w) z[w] += __shfl_xor(z[w], m, 64);
    }

    // ---- linear head, per wave (no cross-wave combine needed) ----
    float tacc = 0.f;
    if (lane < 12){
        #pragma unroll
        for (int w=0; w<12; ++w)
            tacc = fmaf(z[w], Wm[w*12 + lane], tacc);
        tacc = fmaxf(tacc, 0.f);
    }
    #pragma unroll
    for (int m=1; m<16; m<<=1) tacc += __shfl_xor(tacc, m, 64);
    if (lane == 0) out[b] = tacc;
}

extern "C" void kernel_launch(void* const* d_in, const int* in_sizes, int n_in,
                              void* d_out, int out_size, void* d_ws, size_t ws_size,
                              hipStream_t stream) {
    const float* x  = (const float*)d_in[0];
    const float* P  = (const float*)d_in[1];
    const float* Wm = (const float*)d_in[2];
    float* out = (float*)d_out;
    float* ws  = (float*)d_ws;    // 1280 floats = 5 KB
    prep_kernel<<<1, 256, 0, stream>>>(P, ws);
    qnn_kernel<<<BATCH/4, 256, 0, stream>>>(x, ws, Wm, out);
}

// Round 17
// 71.117 us; speedup vs baseline: 1.3640x; 1.3640x over previous
//
#include <hip/hip_runtime.h>

#define NQ 12
#define NLAYERS 8
#define BATCH 1024

typedef float v2f __attribute__((ext_vector_type(2)));

// ---------------------------------------------------------------------------
// R17 = R16 with the init-butterfly component-map bug fixed.
// 4 WAVES PER STATE (wq = 2 wave bits), lean R12/R13 body.
// p = (wq<<10)|(lane<<4)|j ; wire w <-> bit (11-w):
//   wire0 = wq bit1 (q1), wire1 = wq bit0 (q0),
//   wires2..7 = lane bits 5..0, wires8..11 = j bits 3..0 ; j = 2t+k.
// Per layer: ONE full-state LDS exchange carries (a) CNOT-ladder restore
//   q = p^(p>>1) [srcLane = gray(lane)^(q0<<5), src wq=(q1,q0^q1),
//   srcRow = gray2(u)^(lane0<<1), src components (c1^u0, c0^c1)] and (b) the
//   combined RX(w0)*RX(w1) 4-way butterfly (k1..k4 tensor coefficients).
//   For the init butterfly (no restore) src = IDENTITY (R16's bug: it used
//   the gray component map -> j%4 in {2,3} swapped).
// Then RX w2..w11 (permlane32/16 w2/w3, DPP w4..7, local w8..11), fused-RZ.
// 2 barriers/layer; 1024 blocks x 256 thr = 4 waves/SIMD, different blocks
// per SIMD -> decorrelated barrier drains (R13's 36% idle). Wave64 issue
// ceiling is ~50%/wave (R14/R15 measured) -> need >=2 waves/SIMD.
// ---------------------------------------------------------------------------

constexpr int hbit(int m){ int h=0; while(m>>(h+1)) ++h; return 1<<h; }

__device__ __forceinline__ v2f vsplat(float s){ v2f v; v.x=s; v.y=s; return v; }
__device__ __forceinline__ v2f vswap(v2f v){ return __builtin_shufflevector(v, v, 1, 0); }
template<int S> __device__ __forceinline__ v2f msw(v2f v){ if constexpr (S) return vswap(v); else return v; }
__device__ __forceinline__ v2f vfma(v2f a, v2f b, v2f c){ return __builtin_elementwise_fma(a,b,c); }

template<int S>
__device__ __forceinline__ void rx_upd(v2f& ro, v2f& io, v2f r, v2f i, v2f pr, v2f pi,
                                       v2f hc2, v2f hs2, v2f ns2){
    ro = vfma(hc2, r, hs2*msw<S>(pi));
    io = vfma(hc2, i, ns2*msw<S>(pr));
}

#if __has_builtin(__builtin_amdgcn_permlane32_swap) && __has_builtin(__builtin_amdgcn_permlane16_swap)
#define HAVE_PLSWAP 1
#else
#define HAVE_PLSWAP 0
#endif

#if HAVE_PLSWAP
// double-swap (R10/R13-verified): c1 = swap(r,i); c2 = swap(c1[1], c1[0]) ->
//   c2[0] = xorK(r), c2[1] = xorK(i)
__device__ __forceinline__ void xp32(float& pr, float& pi, float r, float i){
    auto c1 = __builtin_amdgcn_permlane32_swap(__float_as_uint(r), __float_as_uint(i), false, false);
    auto c2 = __builtin_amdgcn_permlane32_swap(c1[1], c1[0], false, false);
    pr = __uint_as_float(c2[0]);
    pi = __uint_as_float(c2[1]);
}
__device__ __forceinline__ void xp16(float& pr, float& pi, float r, float i){
    auto c1 = __builtin_amdgcn_permlane16_swap(__float_as_uint(r), __float_as_uint(i), false, false);
    auto c2 = __builtin_amdgcn_permlane16_swap(c1[1], c1[0], false, false);
    pr = __uint_as_float(c2[0]);
    pi = __uint_as_float(c2[1]);
}
#endif

__device__ __forceinline__ float bperm1(int addr, float v){
    return __int_as_float(__builtin_amdgcn_ds_bpermute(addr, __float_as_int(v)));
}

// ---- DPP lane-xor (VALU pipe), LM in [1,15] (R5-proven) ----
template<int CTRL>
__device__ __forceinline__ float dpp1(float v){
    int i = __float_as_int(v);
    return __int_as_float(__builtin_amdgcn_update_dpp(i, i, CTRL, 0xF, 0xF, true));
}
template<int LM>
__device__ __forceinline__ float dppx(float v){
    static_assert(LM >= 1 && LM <= 15, "dpp xor range");
    constexpr int h = (LM >> 2) & 3;
    float r = v;
    if constexpr (h == 1 || h == 2) r = dpp1<0x141>(r);   // row_half_mirror = xor 7
    if constexpr (h == 3 || h == 2) r = dpp1<0x140>(r);   // row_mirror      = xor 15
    constexpr int st = (h==1)?7 : (h==2)?8 : (h==3)?15 : 0;
    constexpr int q = (LM ^ st) & 3;
    if constexpr (q == 1) r = dpp1<0xB1>(r);              // quad_perm xor 1
    if constexpr (q == 2) r = dpp1<0x4E>(r);              // quad_perm xor 2
    if constexpr (q == 3) r = dpp1<0x1B>(r);              // quad_perm xor 3
    return r;
}

// ---- RX, partner fully local (JM on 4-bit j; arrays of 8 v2f) ----
template<int JM>
__device__ __forceinline__ void rx_local8(v2f (&re2)[8], v2f (&im2)[8],
                                          v2f hc2, v2f hs2, v2f ns2){
    if constexpr (JM == 1){
        #pragma unroll
        for (int t=0;t<8;++t){
            v2f r=re2[t], i=im2[t];
            rx_upd<1>(re2[t], im2[t], r, i, r, i, hc2, hs2, ns2);
        }
    } else {
        constexpr int m = JM>>1, HB = hbit(m);
        #pragma unroll
        for (int t=0;t<8;++t){
            if (t & HB) continue;
            const int t2 = t ^ m;
            v2f ru=re2[t], iu=im2[t], rv=re2[t2], iv=im2[t2];
            rx_upd<0>(re2[t],  im2[t],  ru, iu, rv, iv, hc2, hs2, ns2);
            rx_upd<0>(re2[t2], im2[t2], rv, iv, ru, iu, hc2, hs2, ns2);
        }
    }
}

// ---- canonical RX on wire W (2..11) ----
template<int W>
__device__ __forceinline__ void rx_canon8(v2f (&re2)[8], v2f (&im2)[8],
                                          float hc, float hs, int lane){
    const v2f hc2 = vsplat(hc), hs2 = vsplat(hs), ns2 = vsplat(-hs);
    if constexpr (W <= 3){                       // lane bits 5/4
#if HAVE_PLSWAP
        #pragma unroll
        for (int t=0;t<8;++t){
            v2f r=re2[t], i=im2[t];
            float prx,pix,pry,piy;
            if constexpr (W==2){ xp32(prx,pix,r.x,i.x); xp32(pry,piy,r.y,i.y); }
            else               { xp16(prx,pix,r.x,i.x); xp16(pry,piy,r.y,i.y); }
            v2f pr, pi;
            pr.x=prx; pr.y=pry; pi.x=pix; pi.y=piy;
            rx_upd<0>(re2[t], im2[t], r, i, pr, pi, hc2, hs2, ns2);
        }
#else
        const int addr = ((lane ^ (W==2?32:16)) & 63) << 2;
        #pragma unroll
        for (int t=0;t<8;++t){
            v2f r=re2[t], i=im2[t];
            v2f pr, pi;
            pr.x = bperm1(addr, r.x); pr.y = bperm1(addr, r.y);
            pi.x = bperm1(addr, i.x); pi.y = bperm1(addr, i.y);
            rx_upd<0>(re2[t], im2[t], r, i, pr, pi, hc2, hs2, ns2);
        }
#endif
    } else if constexpr (W <= 7){                // lane bits 3..0: DPP
        constexpr int LM = 1<<(7-W);
        #pragma unroll
        for (int t=0;t<8;++t){
            v2f r=re2[t], i=im2[t];
            v2f pr, pi;
            float a0=dppx<LM>(r.x), a1=dppx<LM>(r.y);
            float b0=dppx<LM>(i.x), b1=dppx<LM>(i.y);
            pr.x=a0; pr.y=a1; pi.x=b0; pi.y=b1;
            rx_upd<0>(re2[t], im2[t], r, i, pr, pi, hc2, hs2, ns2);
        }
    } else {                                     // wires 8..11: local
        rx_local8<(1<<(11-W))>(re2, im2, hc2, hs2, ns2);
    }
}

// ---- full-state LDS write: float4 buf[4(wq)][8(row:0-3 re,4-7 im)][64(lane)] ----
__device__ __forceinline__ void exch_write4(const v2f (&re2)[8], const v2f (&im2)[8],
                                            int lane, int wid, float4* buf){
    float4* wr = buf + wid*512 + lane;
    #pragma unroll
    for (int u=0;u<4;++u){
        float4 fr; fr.x=re2[2*u].x; fr.y=re2[2*u].y; fr.z=re2[2*u+1].x; fr.w=re2[2*u+1].y;
        float4 fi; fi.x=im2[2*u].x; fi.y=im2[2*u].y; fi.z=im2[2*u+1].x; fi.w=im2[2*u+1].y;
        wr[u*64]     = fr;
        wr[(4+u)*64] = fi;
    }
}

// component unpack for the RESTORE gray map: src_c = ((c1^u0)<<1)|(c0^c1)
//   u0=0: [x,y,w,z] ; u0=1: [z,w,y,x]   (R11-verified)
__device__ __forceinline__ void unp_gray(const float4 F, bool odd, float (&s)[4]){
    if (!odd){ s[0]=F.x; s[1]=F.y; s[2]=F.w; s[3]=F.z; }
    else     { s[0]=F.z; s[1]=F.w; s[2]=F.y; s[3]=F.x; }
}
// identity unpack (no restore): src_c = c  (R16's bug: used gray map here)
__device__ __forceinline__ void unp_id(const float4 F, float (&s)[4]){
    s[0]=F.x; s[1]=F.y; s[2]=F.z; s[3]=F.w;
}

// ---- combined RX(w0)*RX(w1) 4-way butterfly (+ optional CNOT restore) ----
// new = k1*s00 - i k2*s01 - i k3*s10 - k4*s11
//   real: k1*s00r + k2*s01i + k3*s10i - k4*s11r
//   imag: k1*s00i - k2*s01r - k3*s10r - k4*s11i
template<bool RESTORE>
__device__ __forceinline__ void bfly4(v2f (&re2)[8], v2f (&im2)[8],
                                      float k1, float k2, float k3, float k4,
                                      int lane, int wid, const float4* buf){
    const int q1 = (wid>>1)&1, q0 = wid&1;
    int sl, R00, rb;
    if constexpr (RESTORE){
        const int g = (lane ^ (lane>>1)) & 63;
        sl  = g ^ (q0<<5);
        R00 = (q1<<1) | (q0^q1);
        rb  = (lane & 1) << 1;
    } else {
        sl  = lane;
        R00 = wid;
        rb  = 0;
    }
    // source regions: self; flip wire1 (q0); flip wire0 (q1); flip both.
    // RESTORE: src_wq XORs = 1 / 3 / 2 on R00, with sl^32 wherever q0 flips.
    // no-RESTORE: region XORs = 1 / 2 / 3 on wid, lane unchanged.
    const float4* rd00 = buf + R00*512 + sl;
    const float4* s01p = RESTORE ? (buf + (R00^1)*512 + (sl^32)) : (buf + (R00^1)*512 + sl);
    const float4* s10p = RESTORE ? (buf + (R00^3)*512 + sl)      : (buf + (R00^2)*512 + sl);
    const float4* s11p = RESTORE ? (buf + (R00^2)*512 + (sl^32)) : (buf + (R00^3)*512 + sl);
    #pragma unroll
    for (int u=0;u<4;++u){
        const int row = RESTORE ? ((u ^ (u>>1)) ^ rb) : u;
        const bool odd = (u & 1) != 0;
        float4 Fr00 = rd00[row*64], Fi00 = rd00[(row+4)*64];
        float4 Fr01 = s01p[row*64], Fi01 = s01p[(row+4)*64];
        float4 Fr10 = s10p[row*64], Fi10 = s10p[(row+4)*64];
        float4 Fr11 = s11p[row*64], Fi11 = s11p[(row+4)*64];
        float s00r[4], s00i[4], s01r[4], s01i[4], s10r[4], s10i[4], s11r[4], s11i[4];
        if constexpr (RESTORE){
            unp_gray(Fr00, odd, s00r); unp_gray(Fi00, odd, s00i);
            unp_gray(Fr01, odd, s01r); unp_gray(Fi01, odd, s01i);
            unp_gray(Fr10, odd, s10r); unp_gray(Fi10, odd, s10i);
            unp_gray(Fr11, odd, s11r); unp_gray(Fi11, odd, s11i);
        } else {
            unp_id(Fr00, s00r); unp_id(Fi00, s00i);
            unp_id(Fr01, s01r); unp_id(Fi01, s01i);
            unp_id(Fr10, s10r); unp_id(Fi10, s10i);
            unp_id(Fr11, s11r); unp_id(Fi11, s11i);
        }
        float nr[4], ni[4];
        #pragma unroll
        for (int c=0;c<4;++c){
            nr[c] = fmaf(k1, s00r[c], fmaf(k2, s01i[c], fmaf(k3, s10i[c], -k4*s11r[c])));
            ni[c] = fmaf(k1, s00i[c], fmaf(-k2, s01r[c], fmaf(-k3, s10r[c], -k4*s11i[c])));
        }
        re2[2*u].x = nr[0]; re2[2*u].y = nr[1]; re2[2*u+1].x = nr[2]; re2[2*u+1].y = nr[3];
        im2[2*u].x = ni[0]; im2[2*u].y = ni[1]; im2[2*u+1].x = ni[2]; im2[2*u+1].y = ni[3];
    }
}

// ---- per-layer RX gates w2..w11 ----
template<int W>
__device__ __forceinline__ void gates_w(v2f (&re2)[8], v2f (&im2)[8],
                                        const float2* __restrict__ tb, int lane){
    const float2 t = tb[W];
    rx_canon8<W>(re2, im2, t.x, t.y, lane);
    if constexpr (W+1 < NQ) gates_w<W+1>(re2, im2, tb, lane);
}

// ---- init RX w2..w11 ----
template<int W>
__device__ __forceinline__ void init_w(v2f (&re2)[8], v2f (&im2)[8],
                                       const float* __restrict__ xb, int lane){
    float hs, hc;
    __sincosf(xb[W]*1.5707963267948966f, &hs, &hc);
    rx_canon8<W>(re2, im2, hc, hs, lane);
    if constexpr (W+1 < NQ) init_w<W+1>(re2, im2, xb, lane);
}

// ---------------------------------------------------------------------------
// Workspace (floats): [0,192) tRX float2[8][12]; [192,256) tTH float[8][8]
// (RZ th/2, wires 0..7); [256,512) tJ float4[8][8] (beta over wires 8..11).
// ---------------------------------------------------------------------------
__global__ void prep_kernel(const float* __restrict__ P, float* __restrict__ ws){
    const int i = threadIdx.x;   // 128 threads
    float2* tRX = (float2*)ws;
    float*  tTH = ws + 192;
    float4* tJ  = (float4*)(ws + 256);
    if (i < 96){
        const int l = i/12, w = i%12;
        float2 v; __sincosf(P[l*24 + 2*w]*0.5f, &v.y, &v.x);
        tRX[i] = v;
    }
    if (i < 64){
        const int l = i>>3, w = i&7;
        tTH[i] = P[l*24 + 2*w + 1]*0.5f;   // wires 0..7
        const int t = i&7;
        float br[2], bi[2];
        #pragma unroll
        for (int k=0;k<2;++k){
            const int j = 2*t + k;         // 4-bit j (wires 8..11)
            float beta = 0.f;
            #pragma unroll
            for (int w2=8; w2<12; ++w2){
                const float th = P[l*24 + 2*w2 + 1]*0.5f;
                beta += ((j >> (11-w2)) & 1) ? th : -th;
            }
            __sincosf(beta, &bi[k], &br[k]);
        }
        float4 v; v.x=br[0]; v.y=br[1]; v.z=bi[0]; v.w=bi[1];
        tJ[i] = v;
    }
}

__global__ __launch_bounds__(256, 4) void qnn_kernel(const float* __restrict__ x,
                                                     const float* __restrict__ ws,
                                                     const float* __restrict__ Wm,
                                                     float* __restrict__ out)
{
    __shared__ float4 buf[4*8*64];   // 32 KB
    const int lane = threadIdx.x & 63;
    const int wid  = threadIdx.x >> 6;   // wq: bit1 = wire0 (q1), bit0 = wire1 (q0)
    const int b    = blockIdx.x;

    const float2* tRX = (const float2*)ws;
    const float*  tTH = ws + 192;
    const float4* tJ  = (const float4*)(ws + 256);

    v2f re2[8], im2[8];
    #pragma unroll
    for (int t=0;t<8;++t){ re2[t] = vsplat(0.f); im2[t] = vsplat(0.f); }
    if (threadIdx.x == 0) re2[0].x = 1.0f;

    const float* xb = x + b*NQ;
    init_w<2>(re2, im2, xb, lane);
    {   // init RX(w0), RX(w1) via plain 4-way butterfly (identity src map)
        float s0_, c0_, s1_, c1_;
        __sincosf(xb[0]*1.5707963267948966f, &s0_, &c0_);
        __sincosf(xb[1]*1.5707963267948966f, &s1_, &c1_);
        const float k1 = c0_*c1_, k2 = c0_*s1_, k3 = s0_*c1_, k4 = s0_*s1_;
        exch_write4(re2, im2, lane, wid, buf);
        __syncthreads();
        bfly4<false>(re2, im2, k1, k2, k3, k4, lane, wid, buf);
        __syncthreads();
    }

    #pragma unroll 1
    for (int l = 0; l < NLAYERS; ++l){
        const float2* tb = tRX + l*12;
        const float2 t0 = tb[0], t1 = tb[1];
        const float k1 = t0.x*t1.x, k2 = t0.x*t1.y, k3 = t0.y*t1.x, k4 = t0.y*t1.y;
        exch_write4(re2, im2, lane, wid, buf);
        __syncthreads();
        bfly4<true>(re2, im2, k1, k2, k3, k4, lane, wid, buf);  // restore + RX w0,w1
        gates_w<2>(re2, im2, tb, lane);                         // RX w2..w11

        // ---- fused RZ (all 12 wires) ----
        const float* th = tTH + l*8;
        float alpha = (((wid>>1)&1) ? th[0] : -th[0]) + ((wid&1) ? th[1] : -th[1]);
        #pragma unroll
        for (int w=2; w<=7; ++w)
            alpha += ((lane >> (7-w)) & 1) ? th[w] : -th[w];
        float sa, ca;
        __sincosf(alpha, &sa, &ca);
        const v2f vca = vsplat(ca), vsa = vsplat(sa), vna = vsplat(-sa);
        const float4* tj = tJ + l*8;
        #pragma unroll
        for (int t=0;t<8;++t){
            const float4 J = tj[t];
            v2f jr; jr.x=J.x; jr.y=J.y;
            v2f ji; ji.x=J.z; ji.y=J.w;
            const v2f cr  = vfma(vca, jr, vna*ji);   // cos(a+b)
            const v2f ci  = vfma(vca, ji, vsa*jr);   // sin(a+b)
            const v2f nci = -ci;
            const v2f r = re2[t], m = im2[t];
            re2[t] = vfma(r, cr, m*nci);
            im2[t] = vfma(m, cr, r*ci);
        }
        __syncthreads();
    }

    // ---- PauliZ expvals (canonical state) ----
    v2f S = vsplat(0.f), S8 = vsplat(0.f), S9 = vsplat(0.f), S10 = vsplat(0.f);
    #pragma unroll
    for (int t=0;t<8;++t){
        v2f p2 = __builtin_elementwise_fma(re2[t], re2[t], im2[t]*im2[t]);
        S += p2;
        S8  += (t&4)? -p2 : p2;   // wire 8  (t bit2)
        S9  += (t&2)? -p2 : p2;   // wire 9
        S10 += (t&1)? -p2 : p2;   // wire 10
    }
    const float s0 = S.x + S.y;

    float z[12];
    z[0] = ((wid>>1)&1) ? -s0 : s0;
    z[1] = (wid&1)      ? -s0 : s0;
    #pragma unroll
    for (int w=2; w<=7; ++w) z[w] = ((lane >> (7-w)) & 1) ? -s0 : s0;
    z[8]  = S8.x + S8.y;
    z[9]  = S9.x + S9.y;
    z[10] = S10.x + S10.y;
    z[11] = S.x - S.y;             // wire 11 (component)

    #pragma unroll
    for (int m=1; m<64; m<<=1){
        #pragma unroll
        for (int w=0; w<12; ++w) z[w] += __shfl_xor(z[w], m, 64);
    }

    float* sh = (float*)buf;
    if (lane == 0){
        #pragma unroll
        for (int w=0; w<12; ++w) sh[wid*12 + w] = z[w];
    }
    __syncthreads();
    if (wid == 0){
        float tacc = 0.f;
        if (lane < 12){
            #pragma unroll
            for (int w=0; w<12; ++w){
                const float zz = sh[w] + sh[12+w] + sh[24+w] + sh[36+w];
                tacc = fmaf(zz, Wm[w*12 + lane], tacc);
            }
            tacc = fmaxf(tacc, 0.f);
        }
        #pragma unroll
        for (int m=1; m<16; m<<=1) tacc += __shfl_xor(tacc, m, 64);
        if (lane == 0) out[b] = tacc;
    }
}

extern "C" void kernel_launch(void* const* d_in, const int* in_sizes, int n_in,
                              void* d_out, int out_size, void* d_ws, size_t ws_size,
                              hipStream_t stream) {
    const float* x  = (const float*)d_in[0];
    const float* P  = (const float*)d_in[1];
    const float* Wm = (const float*)d_in[2];
    float* out = (float*)d_out;
    float* ws  = (float*)d_ws;    // 512 floats = 2 KB
    prep_kernel<<<1, 128, 0, stream>>>(P, ws);
    qnn_kernel<<<BATCH, 256, 0, stream>>>(x, ws, Wm, out);
}